// Round 3
// baseline (654.383 us; speedup 1.0000x reference)
//
#include <hip/hip_runtime.h>

// Problem constants (fixed by the reference)
#define V 3
#define A 4
#define NN 50000
#define C 128
#define C4 32                        // C in float4 units
#define CHUNKS 256                   // row chunks per (v,a) in the column-sum kernel
#define ROWS_PER ((NN + CHUNKS - 1) / CHUNKS)   // 196
#define VA (V * A)                   // 12

typedef float nf4 __attribute__((ext_vector_type(4)));  // native vec4 for nontemporal store

__device__ __forceinline__ float dot4(float4 a, float4 b) {
    return a.x * b.x + a.y * b.y + a.z * b.z + a.w * b.w;
}

__device__ __forceinline__ float fast_tanh(float x) {
    float ax = fminf(fabsf(x), 15.f);
    float e  = __expf(2.f * ax);
    float r  = (e - 1.f) * __frcp_rn(e + 1.f);
    return copysignf(r, x);
}

// ---------------------------------------------------------------------------
// tvec for one va (run by the LAST colsum block of that va):
// reduce partials -> sbar; t[va,c] = sum_d sbar[d]*W[v,d,c]; c0 = sbar . b
// 256 threads, split-K across the two thread halves.
// ---------------------------------------------------------------------------
__device__ __forceinline__ void tvec_task(const float* __restrict__ part,
                                          const float* __restrict__ W,
                                          const float* __restrict__ b,
                                          float* __restrict__ t,
                                          float* __restrict__ c0, int va) {
    const int v    = va / A;
    const int c    = threadIdx.x & 127; // 0..127
    const int half = threadIdx.x >> 7;  // 0 or 1

    // --- chunk reduction, split across the two halves (128 chunks each) ---
    float acc = 0.f;
    #pragma unroll 8
    for (int ch = half * (CHUNKS / 2); ch < half * (CHUNKS / 2) + (CHUNKS / 2); ch++)
        acc += part[((size_t)ch * VA + va) * C + c];

    __shared__ float red[2][C];
    __shared__ float sb[C];
    __shared__ float pb[C];
    red[half][c] = acc;
    __syncthreads();
    if (threadIdx.x < C)
        sb[c] = (red[0][c] + red[1][c]) * (1.0f / (float)NN);
    __syncthreads();

    // --- t[va,c] = sum_d sb[d] * W[v,d,c], split-K over the two halves ---
    const float* Wv = W + (size_t)v * C * C;
    float t_acc = 0.f;
    #pragma unroll 8
    for (int d = half * 64; d < half * 64 + 64; d++)
        t_acc += sb[d] * Wv[d * C + c];
    red[half][c] = t_acc;
    __syncthreads();
    if (threadIdx.x < C) {
        t[va * C + c] = red[0][c] + red[1][c];
        pb[c] = sb[c] * b[v * C + c];
    }
    __syncthreads();
    #pragma unroll
    for (int s = 64; s > 0; s >>= 1) {
        if (threadIdx.x < s) pb[threadIdx.x] += pb[threadIdx.x + s];
        __syncthreads();
    }
    if (threadIdx.x == 0) c0[va] = pb[0];
}

// ---------------------------------------------------------------------------
// K1: partial column sums with 8 independent load streams per thread
// (8 x float4 in flight -> covers ~1 us loaded HBM latency; the R2 version
// kept <=2 in flight at VGPR_Count=24 and ran at 9% of HBM peak).
// part[chunk][va][c] = sum over this chunk's rows of x[va][n][c]
// grid = (CHUNKS, VA), block = 256.  Last block per va computes tvec.
// ---------------------------------------------------------------------------
__global__ void k_colsum(const float* __restrict__ x, const float* __restrict__ W,
                         const float* __restrict__ b, float* __restrict__ part,
                         float* __restrict__ t, float* __restrict__ c0,
                         int* __restrict__ cnt) {
    const int va    = blockIdx.y;
    const int chunk = blockIdx.x;
    const int n0 = chunk * ROWS_PER;
    const int n1 = (n0 + ROWS_PER < NN) ? (n0 + ROWS_PER) : NN;

    const int lane4 = threadIdx.x & 31;   // float4 index within the row
    const int rowIn = threadIdx.x >> 5;   // 0..7

    const float4* xp = (const float4*)(x + (size_t)va * NN * C);

    float4 a0 = {0,0,0,0}, a1 = {0,0,0,0}, a2 = {0,0,0,0}, a3 = {0,0,0,0};
    float4 a4 = {0,0,0,0}, a5 = {0,0,0,0}, a6 = {0,0,0,0}, a7 = {0,0,0,0};

    int n = n0 + rowIn;
    // main loop: 8 independent 16B loads in flight per thread (64 rows/iter/block)
    for (; n + 56 < n1; n += 64) {
        float4 v0 = xp[(size_t)(n     ) * C4 + lane4];
        float4 v1 = xp[(size_t)(n +  8) * C4 + lane4];
        float4 v2 = xp[(size_t)(n + 16) * C4 + lane4];
        float4 v3 = xp[(size_t)(n + 24) * C4 + lane4];
        float4 v4 = xp[(size_t)(n + 32) * C4 + lane4];
        float4 v5 = xp[(size_t)(n + 40) * C4 + lane4];
        float4 v6 = xp[(size_t)(n + 48) * C4 + lane4];
        float4 v7 = xp[(size_t)(n + 56) * C4 + lane4];
        a0.x += v0.x; a0.y += v0.y; a0.z += v0.z; a0.w += v0.w;
        a1.x += v1.x; a1.y += v1.y; a1.z += v1.z; a1.w += v1.w;
        a2.x += v2.x; a2.y += v2.y; a2.z += v2.z; a2.w += v2.w;
        a3.x += v3.x; a3.y += v3.y; a3.z += v3.z; a3.w += v3.w;
        a4.x += v4.x; a4.y += v4.y; a4.z += v4.z; a4.w += v4.w;
        a5.x += v5.x; a5.y += v5.y; a5.z += v5.z; a5.w += v5.w;
        a6.x += v6.x; a6.y += v6.y; a6.z += v6.z; a6.w += v6.w;
        a7.x += v7.x; a7.y += v7.y; a7.z += v7.z; a7.w += v7.w;
    }
    // tail rows
    for (; n < n1; n += 8) {
        float4 v = xp[(size_t)n * C4 + lane4];
        a0.x += v.x; a0.y += v.y; a0.z += v.z; a0.w += v.w;
    }
    // combine streams (tree)
    a0.x += a1.x; a0.y += a1.y; a0.z += a1.z; a0.w += a1.w;
    a2.x += a3.x; a2.y += a3.y; a2.z += a3.z; a2.w += a3.w;
    a4.x += a5.x; a4.y += a5.y; a4.z += a5.z; a4.w += a5.w;
    a6.x += a7.x; a6.y += a7.y; a6.z += a7.z; a6.w += a7.w;
    a0.x += a2.x; a0.y += a2.y; a0.z += a2.z; a0.w += a2.w;
    a4.x += a6.x; a4.y += a6.y; a4.z += a6.z; a4.w += a6.w;
    a0.x += a4.x; a0.y += a4.y; a0.z += a4.z; a0.w += a4.w;

    __shared__ float4 redA[256];
    redA[threadIdx.x] = a0;
    __syncthreads();
    if (threadIdx.x < 32) {
        float4 tv = redA[threadIdx.x];
        #pragma unroll
        for (int r = 1; r < 8; r++) {
            float4 o = redA[threadIdx.x + 32 * r];
            tv.x += o.x; tv.y += o.y; tv.z += o.z; tv.w += o.w;
        }
        ((float4*)part)[((size_t)chunk * VA + va) * C4 + lane4] = tv;
    }
    __syncthreads();   // partial store drained before the ticket

    // --- per-va completion ticket ---
    __shared__ int isLast;
    if (threadIdx.x == 0) {
        __threadfence();                       // release our partials device-wide
        int old = atomicAdd(&cnt[va], 1);      // device-scope by default on gfx950
        isLast = (old == CHUNKS - 1);
    }
    __syncthreads();
    if (isLast) {
        __threadfence();                       // acquire before reading others' partials
        tvec_task(part, W, b, t, c0, va);
    }
}

// ---------------------------------------------------------------------------
// K2: fused scores -> tanh -> softmax over V -> weighted combine.
// One 32-lane group handles FOUR consecutive nodes (12 independent x-loads
// in flight per thread). Reverse node order for L3 reuse of colsum's tail;
// nontemporal output stores keep x resident in L3.
// grid = (ceil(NN/32), A), block = 256 (8 groups x 4 nodes = 32 nodes/block)
// ---------------------------------------------------------------------------
__global__ void k_main(const float* __restrict__ x, const float* __restrict__ t,
                       const float* __restrict__ c0, float* __restrict__ out) {
    const int lane = threadIdx.x & 31;
    const int grp  = threadIdx.x >> 5;            // 0..7
    const int a    = blockIdx.y;
    // reverse mapping: bx=0 -> last 32 nodes (most recently cached by colsum)
    const int n0   = (NN - 32 * (blockIdx.x + 1)) + grp * 4;
    if (n0 < 0) return;   // tail block: groups below node 0 exit whole

    const size_t vstride = (size_t)A * NN * C4;   // view stride in float4 units
    const float4* xp = (const float4*)x;
    const size_t base = ((size_t)a * NN + n0) * C4 + lane;

    // 12 independent 16B loads per thread (4 nodes x 3 views)
    float4 x00 = xp[base           ];
    float4 x01 = xp[base +     C4  ];
    float4 x02 = xp[base + 2 * C4  ];
    float4 x03 = xp[base + 3 * C4  ];
    float4 x10 = xp[base           + vstride];
    float4 x11 = xp[base +     C4  + vstride];
    float4 x12 = xp[base + 2 * C4  + vstride];
    float4 x13 = xp[base + 3 * C4  + vstride];
    float4 x20 = xp[base           + 2 * vstride];
    float4 x21 = xp[base +     C4  + 2 * vstride];
    float4 x22 = xp[base + 2 * C4  + 2 * vstride];
    float4 x23 = xp[base + 3 * C4  + 2 * vstride];

    const float4* tp = (const float4*)t;
    float4 t0 = tp[(0 * A + a) * C4 + lane];
    float4 t1 = tp[(1 * A + a) * C4 + lane];
    float4 t2 = tp[(2 * A + a) * C4 + lane];

    float d00 = dot4(x00, t0), d01 = dot4(x01, t0), d02 = dot4(x02, t0), d03 = dot4(x03, t0);
    float d10 = dot4(x10, t1), d11 = dot4(x11, t1), d12 = dot4(x12, t1), d13 = dot4(x13, t1);
    float d20 = dot4(x20, t2), d21 = dot4(x21, t2), d22 = dot4(x22, t2), d23 = dot4(x23, t2);

    #pragma unroll
    for (int off = 16; off > 0; off >>= 1) {
        d00 += __shfl_xor(d00, off, 32); d01 += __shfl_xor(d01, off, 32);
        d02 += __shfl_xor(d02, off, 32); d03 += __shfl_xor(d03, off, 32);
        d10 += __shfl_xor(d10, off, 32); d11 += __shfl_xor(d11, off, 32);
        d12 += __shfl_xor(d12, off, 32); d13 += __shfl_xor(d13, off, 32);
        d20 += __shfl_xor(d20, off, 32); d21 += __shfl_xor(d21, off, 32);
        d22 += __shfl_xor(d22, off, 32); d23 += __shfl_xor(d23, off, 32);
    }

    const float cc0 = c0[0 * A + a], cc1 = c0[1 * A + a], cc2 = c0[2 * A + a];

    nf4* op = (nf4*)out;
    const size_t obase = ((size_t)a * NN + n0) * C4 + lane;

    // per-node: tanh -> softmax over the 3 views -> weighted combine -> store
#define NODE(J, S0, S1, S2, X0, X1, X2)                                          \
    {                                                                            \
        float s0 = fast_tanh(S0 + cc0);                                          \
        float s1 = fast_tanh(S1 + cc1);                                          \
        float s2 = fast_tanh(S2 + cc2);                                          \
        float m  = fmaxf(s0, fmaxf(s1, s2));                                     \
        float e0 = __expf(s0 - m), e1 = __expf(s1 - m), e2 = __expf(s2 - m);     \
        float inv = __frcp_rn(e0 + e1 + e2);                                     \
        float w0 = e0 * inv, w1 = e1 * inv, w2 = e2 * inv;                       \
        nf4 o;                                                                   \
        o.x = w0 * X0.x + w1 * X1.x + w2 * X2.x;                                 \
        o.y = w0 * X0.y + w1 * X1.y + w2 * X2.y;                                 \
        o.z = w0 * X0.z + w1 * X1.z + w2 * X2.z;                                 \
        o.w = w0 * X0.w + w1 * X1.w + w2 * X2.w;                                 \
        __builtin_nontemporal_store(o, op + obase + (J) * C4);                   \
    }

    NODE(0, d00, d10, d20, x00, x10, x20)
    NODE(1, d01, d11, d21, x01, x11, x21)
    NODE(2, d02, d12, d22, x02, x12, x22)
    NODE(3, d03, d13, d23, x03, x13, x23)
#undef NODE
}

// ---------------------------------------------------------------------------
extern "C" void kernel_launch(void* const* d_in, const int* in_sizes, int n_in,
                              void* d_out, int out_size, void* d_ws, size_t ws_size,
                              hipStream_t stream) {
    const float* x = (const float*)d_in[0];
    const float* W = (const float*)d_in[1];
    const float* b = (const float*)d_in[2];
    float* out = (float*)d_out;

    float* part = (float*)d_ws;                   // CHUNKS*VA*C floats (~1.6 MB)
    float* t    = part + (size_t)CHUNKS * VA * C; // VA*C floats
    float* c0   = t + VA * C;                     // VA floats
    int*   cnt  = (int*)(c0 + VA);                // VA ints (ticket counters)

    // ws is poisoned by the harness each iteration -> zero the tickets.
    hipMemsetAsync(cnt, 0, VA * sizeof(int), stream);

    k_colsum<<<dim3(CHUNKS, VA), 256, 0, stream>>>(x, W, b, part, t, c0, cnt);
    k_main<<<dim3((NN + 31) / 32, A), 256, 0, stream>>>(x, t, c0, out);
}